// Round 2
// baseline (213.554 us; speedup 1.0000x reference)
//
#include <hip/hip_runtime.h>

namespace {
constexpr int CC     = 10;                 // cluster gap window C
constexpr int TT     = 500;                // time steps
constexpr int NN     = 128;                // neurons per batch row == blockDim
constexpr int KMAX   = TT / (CC + 1) + 1;  // 46: max possible clusters
constexpr int NCHUNK = TT / CC;            // 50 chunks of 10
}

__global__ void zero_loss_kernel(float* out) {
    if (threadIdx.x == 0) out[0] = 0.0f;
}

__global__ __launch_bounds__(NN, 1)
void atca_tca_loss_kernel(const float* __restrict__ vmem,
                          const int*   __restrict__ labels,
                          float*       __restrict__ out) {
    const int b = blockIdx.x;
    const int n = threadIdx.x;
    const float* __restrict__ src = vmem + (size_t)b * TT * NN + n;
    const int label = labels[b * NN + n];

    __shared__ float clmax[KMAX][NN];   // per-thread column of cluster span-maxes
    __shared__ float redbuf[2];

    // rotating chunk buffers: chunk k lives in slot k&3
    float b0[CC], b1[CC], b2[CC], b3[CC];

    // streaming state (all updated branchlessly)
    int   ls   = -(1 << 20);        // last spike time
    int   nc   = 0;                 // cluster count
    float ccm  = -1e30f;            // current cluster span max
    float rmax = -1e30f;            // max of v since last spike
    float vmax = -1e30f;            // global max
    int   tm   = 0;                 // first argmax
    float m0   = -1e30f;            // max over unmasked positions
    int   hasu = 0;                 // any unmasked position exists (== !full0)

    auto load = [&](float (&d)[CC], int k) {
        const float* p = src + (size_t)k * CC * NN;
        #pragma unroll
        for (int j = 0; j < CC; ++j) d[j] = p[(size_t)j * NN];
    };

    // process one chunk; vp holds v[t-C] (= previous chunk), doM0 folds at compile time
    auto proc = [&](const float (&vv)[CC], const float (&vp)[CC], int tc, bool doM0) {
        #pragma unroll
        for (int j = 0; j < CC; ++j) {
            const int   t   = tc + j;
            const float v   = vv[j];
            const float rm2 = fmaxf(rmax, v);
            const bool  spike   = v >= 0.0f;
            const bool  isStart = spike && (t - ls > CC);
            nc += isStart ? 1 : 0;
            const float cont = fmaxf(ccm, rm2);
            ccm  = isStart ? v : (spike ? cont : ccm);
            rmax = spike ? -1e30f : rm2;
            ls   = spike ? t : ls;
            const bool better = v > vmax;     // strict > keeps first argmax
            vmax = better ? v : vmax;
            tm   = better ? t : tm;
            if (doM0) {
                // u = t - C is unmasked <=> no spike in [u-C, u+C] <=> ls < t - 2C
                const float vu = vp[j];
                const bool  um = ls < t - 2 * CC;
                m0 = (um && vu > m0) ? vu : m0;
                hasu |= (int)um;
            }
            const int idx = nc > 0 ? nc - 1 : 0;
            clmax[idx][n] = ccm;              // unconditional store; final value per slot wins
        }
    };

    // ---- main pass: 4-slot rotation, load chunk k+2 before processing chunk k ----
    load(b0, 0); load(b1, 1);
    load(b2, 2); proc(b0, b3, 0, false);      // chunk 0 (vp unused)
    load(b3, 3); proc(b1, b0, CC, true);      // chunk 1
    for (int k = 2; k < NCHUNK; k += 4) {     // chunks 2..49, 12 iterations
        if (k + 2 < NCHUNK) load(b0, k + 2);
        proc(b2, b1, k * CC, true);
        if (k + 3 < NCHUNK) load(b1, k + 3);
        proc(b3, b2, (k + 1) * CC, true);
        if (k + 4 < NCHUNK) load(b2, k + 4);
        proc(b0, b3, (k + 2) * CC, true);
        if (k + 5 < NCHUNK) load(b3, k + 5);
        proc(b1, b0, (k + 3) * CC, true);
    }
    // epilogue: trailing u = T-C .. T-1 (chunk 49 ended in b1; ls is final)
    #pragma unroll
    for (int j = 0; j < CC; ++j) {
        const int   u  = (TT - CC) + j;
        const float vu = b1[j];
        const bool  um = ls < u - CC;
        m0 = (um && vu > m0) ? vu : m0;
        hasu |= (int)um;
    }

    // -------- optional pass 2: m_rest (rare; wave-uniform gate) --------
    const bool need2 = (label > nc) && hasu && (label - nc >= 2);
    float m2 = -1e30f;
    int   has2 = 0;
    if (__any((int)need2)) {
        const int wlo = tm - CC / 2, whi = tm + CC / 2;
        int ls2 = -(1 << 20);
        auto proc2 = [&](const float (&vv)[CC], const float (&vp)[CC], int tc, bool doM) {
            #pragma unroll
            for (int j = 0; j < CC; ++j) {
                const int   t = tc + j;
                const float v = vv[j];
                ls2 = (v >= 0.0f) ? t : ls2;
                if (doM) {
                    const int   u  = t - CC;
                    const float vu = vp[j];
                    const bool  um = (ls2 < t - 2 * CC) && (u < wlo || u > whi);
                    m2 = (um && vu > m2) ? vu : m2;
                    has2 |= (int)um;
                }
            }
        };
        load(b0, 0); load(b1, 1);
        load(b2, 2); proc2(b0, b3, 0, false);
        load(b3, 3); proc2(b1, b0, CC, true);
        for (int k = 2; k < NCHUNK; k += 4) {
            if (k + 2 < NCHUNK) load(b0, k + 2);
            proc2(b2, b1, k * CC, true);
            if (k + 3 < NCHUNK) load(b1, k + 3);
            proc2(b3, b2, (k + 1) * CC, true);
            if (k + 4 < NCHUNK) load(b2, k + 4);
            proc2(b0, b3, (k + 2) * CC, true);
            if (k + 5 < NCHUNK) load(b3, k + 5);
            proc2(b1, b0, (k + 3) * CC, true);
        }
        #pragma unroll
        for (int j = 0; j < CC; ++j) {
            const int   u  = (TT - CC) + j;
            const float vu = b1[j];
            const bool  um = (ls2 < u - CC) && (u < wlo || u > whi);
            m2 = (um && vu > m2) ? vu : m2;
            has2 |= (int)um;
        }
    }

    __syncthreads();   // clmax writes visible before selection reads

    // -------- branch select --------
    float contrib = 0.0f;
    if (label > nc) {
        if (!hasu) {
            contrib = vmax;                         // full0 -> vmax
        } else {
            const float dE = (float)(label - nc);   // >= 1
            const float mrest = has2 ? m2 : vmax;   // full2 -> vmax surrogate
            contrib = -((m0 + (dE - 1.0f) * mrest) / dE);
        }
    } else if (label < nc) {
        const int k = nc - label;                   // 1..nc
        float s = 0.0f;
        float used[KMAX / 4];                       // not needed; selection via LDS marking
        (void)used;
        for (int i = 0; i < k; ++i) {               // sum k smallest cluster maxes
            float mn = 1e30f; int mj = 0;
            for (int jj = 0; jj < nc; ++jj) {
                const float x = clmax[jj][n];
                if (x < mn) { mn = x; mj = jj; }
            }
            s += mn;
            clmax[mj][n] = 1e30f;                   // mark used
        }
        contrib = s / (float)k;
    }

    // spike_output
    out[1 + b * NN + n] = (float)nc;

    // loss reduction: wave shuffle -> LDS -> one atomic per block
    float wsum = contrib;
    #pragma unroll
    for (int off = 32; off > 0; off >>= 1)
        wsum += __shfl_down(wsum, off, 64);
    if ((n & 63) == 0) redbuf[n >> 6] = wsum;
    __syncthreads();
    if (n == 0) atomicAdd(out, redbuf[0] + redbuf[1]);
}

extern "C" void kernel_launch(void* const* d_in, const int* in_sizes, int n_in,
                              void* d_out, int out_size, void* d_ws, size_t ws_size,
                              hipStream_t stream) {
    const float* vmem   = (const float*)d_in[0];
    // d_in[1] (vlastmem) and d_in[3] (ratio) are unused by the reference forward.
    const int*   labels = (const int*)d_in[2];
    float*       out    = (float*)d_out;

    const int B = in_sizes[2] / NN;   // 256

    hipLaunchKernelGGL(zero_loss_kernel, dim3(1), dim3(64), 0, stream, out);
    hipLaunchKernelGGL(atca_tca_loss_kernel, dim3(B), dim3(NN), 0, stream,
                       vmem, labels, out);
}

// Round 3
// 208.205 us; speedup vs baseline: 1.0257x; 1.0257x over previous
//
#include <hip/hip_runtime.h>

namespace {
constexpr int CC   = 10;                  // cluster gap window C
constexpr int TT   = 500;                 // time steps
constexpr int NN   = 128;                 // neurons per batch row
constexpr int G    = 4;                   // t-segments per neuron
constexpr int L    = TT / G;              // 125 core steps per segment
constexpr int CH   = 5;                   // chunk size
constexpr int NCH  = (L + 2 * CC) / CH;   // 29 chunks cover [a-10, b+10)
constexpr int MAXLOC = L / (CC + 1) + 1;  // 12 max local clusters per segment
}

__global__ void zero_loss_kernel(float* out) {
    if (threadIdx.x == 0) out[0] = 0.0f;
}

__global__ __launch_bounds__(256)
void atca_tca_loss_kernel(const float* __restrict__ vmem,
                          const int*   __restrict__ labels,
                          float*       __restrict__ out) {
    const int s    = threadIdx.x >> 6;          // segment 0..3 (== wave id)
    const int lane = threadIdx.x & 63;          // neuron within half-row
    const int bb   = blockIdx.x;
    const int b    = bb >> 1;
    const int n    = ((bb & 1) << 6) | lane;    // global neuron 0..127
    const float* __restrict__ col = vmem + (size_t)b * TT * NN + n;
    const int a = s * L;                        // core start

    // per-segment results, indexed [seg*64 + lane]
    __shared__ float s_loc[G * MAXLOC * 64];    // local cluster span-maxes (also reused as compact global list)
    __shared__ int   s_ncs[G * 64];
    __shared__ float s_hdm[G * 64];
    __shared__ int   s_hdn[G * 64];
    __shared__ float s_tg [G * 64];
    __shared__ float s_vmx[G * 64];
    __shared__ int   s_tm [G * 64];
    __shared__ float s_m0 [G * 64];
    __shared__ int   s_hu [G * 64];

    const bool segFirst = (s == 0);
    const bool segLast  = (s == G - 1);

    // ---------------- segment scan over [a-10, b+10), 29 chunks of 5 ----------------
    float buf[6][CH];                           // chunk k lives in slot k%6
    int   ls = -(1 << 20);                      // last spike time (halo-aware)
    int   lcount = 0;                           // local cluster starts
    float ccm  = -1e30f;                        // open local cluster span max
    float rmax = -1e30f;                        // max since last core spike
    float hdmax = -1e30f;                       // head (incoming-cluster piece) max over [a, last head spike]
    int   hdne = 0;
    float vmx = -1e30f; int tmn = 0;            // segment vmax / argmax
    float m0 = -1e30f;  int hasu = 0;

    #pragma unroll
    for (int k = 0; k < 3; ++k) {               // prologue loads: chunks 0..2
        #pragma unroll
        for (int j = 0; j < CH; ++j) {
            const int ofs = CH * k + j - CC;
            int t = a + ofs;
            t = t < 0 ? 0 : (t >= TT ? TT - 1 : t);
            buf[k][j] = col[(size_t)t * NN];
        }
    }

    #pragma unroll
    for (int k = 0; k < NCH; ++k) {
        if (k + 3 < NCH) {                      // prefetch chunk k+3 (distance 3 = 15 loads in flight)
            const int slot = (k + 3) % 6;
            #pragma unroll
            for (int j = 0; j < CH; ++j) {
                const int ofs = CH * (k + 3) + j - CC;
                int t = a + ofs;
                t = t < 0 ? 0 : (t >= TT ? TT - 1 : t);
                buf[slot][j] = col[(size_t)t * NN];
            }
        }
        const int slot  = k % 6;
        const int pslot = (k + 4) % 6;          // chunk k-2 (holds v[t-10])
        #pragma unroll
        for (int j = 0; j < CH; ++j) {
            const int ofs = CH * k + j - CC;    // t - a, compile-time after unroll
            const int t = a + ofs;
            float v = buf[slot][j];
            if (ofs < 0  && segFirst) v = -1.0f;    // before t=0: no data
            if (ofs >= L && segLast)  v = -1.0f;    // past t=T: no data
            const bool spike = v >= 0.0f;
            if (ofs >= 0 && ofs < L) {          // core accounting (compile-time guard)
                const float rm2 = fmaxf(rmax, v);
                if (spike) {
                    if (t - ls > CC) {          // exact: halo provides full C history
                        if (lcount > 0)
                            s_loc[(s * MAXLOC + lcount - 1) * 64 + lane] = ccm;
                        ccm = v; ++lcount;
                    } else if (lcount == 0) {   // continues the incoming cluster
                        hdne = 1; hdmax = fmaxf(hdmax, rm2);
                    } else {
                        ccm = fmaxf(ccm, rm2);
                    }
                    rmax = -1e30f;
                } else {
                    rmax = rm2;
                }
                if (v > vmx) { vmx = v; tmn = t; }  // strict > keeps first argmax
            }
            if (spike) ls = t;                  // halo spikes count for ls
            if (ofs >= CC) {                    // evaluate u = t-10 (always a core u)
                const float vu = buf[pslot][j];
                if (ls < t - 2 * CC) { hasu = 1; if (vu > m0) m0 = vu; }
            }
        }
    }
    if (lcount > 0) s_loc[(s * MAXLOC + lcount - 1) * 64 + lane] = ccm;
    s_ncs[s * 64 + lane] = lcount;
    s_hdm[s * 64 + lane] = hdmax;
    s_hdn[s * 64 + lane] = hdne;
    s_tg [s * 64 + lane] = rmax;                // tail gap: max over (last core spike, b)
    s_vmx[s * 64 + lane] = vmx;
    s_tm [s * 64 + lane] = tmn;
    s_m0 [s * 64 + lane] = m0;
    s_hu [s * 64 + lane] = hasu;

    __syncthreads();

    // ---------------- merge + epilogue: wave 0, one lane per neuron ----------------
    if (threadIdx.x < 64) {
        int   g_nc = 0, g_hasu = 0, g_tm = 0;
        float g_vmax = -1e30f, g_m0 = -1e30f;
        #pragma unroll
        for (int s2 = 0; s2 < G; ++s2) {
            g_nc   += s_ncs[s2 * 64 + lane];
            g_hasu |= s_hu [s2 * 64 + lane];
            const float vv = s_vmx[s2 * 64 + lane];
            if (vv > g_vmax) { g_vmax = vv; g_tm = s_tm[s2 * 64 + lane]; }
            const float mm = s_m0[s2 * 64 + lane];
            if (mm > g_m0) g_m0 = mm;
        }

        // stitch boundary-crossing clusters; compact global list in place into s_loc[g*64+lane]
        int g = 0; bool open = false; float cur = -1e30f; int lastseg = 0;
        #pragma unroll
        for (int s2 = 0; s2 < G; ++s2) {
            const int k   = s_ncs[s2 * 64 + lane];
            const int hne = s_hdn[s2 * 64 + lane];
            if (open) {
                if (hne) {  // cluster continues: add prev tail gap + this head piece
                    cur = fmaxf(cur, fmaxf(s_tg[lastseg * 64 + lane],
                                           s_hdm[s2 * 64 + lane]));
                    lastseg = s2;
                }
                if (k > 0 || !hne) { s_loc[g * 64 + lane] = cur; ++g; open = false; }
            }
            if (k > 0) {
                for (int i = 0; i < k - 1; ++i) {
                    const float x = s_loc[(s2 * MAXLOC + i) * 64 + lane];
                    s_loc[g * 64 + lane] = x; ++g;   // write idx <= read idx: safe
                }
                cur = s_loc[(s2 * MAXLOC + (k - 1)) * 64 + lane];
                open = true; lastseg = s2;
            }
        }
        if (open) { s_loc[g * 64 + lane] = cur; ++g; }
        // g == g_nc by construction

        const int label = labels[b * NN + n];
        float contrib = 0.0f;
        if (label > g_nc) {
            if (!g_hasu) {
                contrib = g_vmax;                       // full0 -> vmax
            } else {
                float mrest = g_vmax;                   // full2 surrogate
                const bool need2 = (label - g_nc >= 2);
                if (__any((int)need2)) {
                    if (need2) {                        // rare serial pass (L2-warm)
                        const int wlo = g_tm - CC / 2, whi = g_tm + CC / 2;
                        int ls2 = -(1 << 20);
                        float m2 = -1e30f; int has2 = 0;
                        for (int c = 0; c < TT / CC + 1; ++c) {
                            float cv[CC], pv[CC];
                            #pragma unroll
                            for (int j = 0; j < CC; ++j) {
                                const int t = c * CC + j;
                                cv[j] = (t < TT) ? col[(size_t)t * NN] : -1.0f;
                            }
                            #pragma unroll
                            for (int j = 0; j < CC; ++j) {
                                const int u = c * CC + j - CC;
                                pv[j] = (u >= 0 && u < TT) ? col[(size_t)u * NN] : -1.0f;
                            }
                            #pragma unroll
                            for (int j = 0; j < CC; ++j) {
                                const int t = c * CC + j;
                                const float v = cv[j];
                                if (v >= 0.0f) ls2 = t;
                                const int u = t - CC;
                                if (u >= 0 && u < TT) {
                                    if (ls2 < t - 2 * CC && (u < wlo || u > whi)) {
                                        has2 = 1;
                                        const float vu = pv[j];
                                        if (vu > m2) m2 = vu;
                                    }
                                }
                            }
                        }
                        if (has2) mrest = m2;
                    }
                }
                const float dE = (float)(label - g_nc);   // >= 1
                contrib = -((g_m0 + (dE - 1.0f) * mrest) / dE);
            }
        } else if (label < g_nc) {
            const int kk = g_nc - label;                  // 1..nc
            float ssum = 0.0f;
            for (int i = 0; i < kk; ++i) {                // sum kk smallest cluster maxes
                float mn = 1e30f; int mj = 0;
                for (int jj = 0; jj < g_nc; ++jj) {
                    const float x = s_loc[jj * 64 + lane];
                    if (x < mn) { mn = x; mj = jj; }
                }
                ssum += mn;
                s_loc[mj * 64 + lane] = 1e30f;            // mark used
            }
            contrib = ssum / (float)kk;
        }

        out[1 + b * NN + n] = (float)g_nc;                // spike_output

        float w = contrib;                                // wave-0 reduction
        #pragma unroll
        for (int off = 32; off > 0; off >>= 1)
            w += __shfl_down(w, off, 64);
        if (lane == 0) atomicAdd(out, w);
    }
}

extern "C" void kernel_launch(void* const* d_in, const int* in_sizes, int n_in,
                              void* d_out, int out_size, void* d_ws, size_t ws_size,
                              hipStream_t stream) {
    const float* vmem   = (const float*)d_in[0];
    // d_in[1] (vlastmem) and d_in[3] (ratio) are unused by the reference forward.
    const int*   labels = (const int*)d_in[2];
    float*       out    = (float*)d_out;

    const int B = in_sizes[2] / NN;   // 256

    hipLaunchKernelGGL(zero_loss_kernel, dim3(1), dim3(64), 0, stream, out);
    hipLaunchKernelGGL(atca_tca_loss_kernel, dim3(2 * B), dim3(256), 0, stream,
                       vmem, labels, out);
}

// Round 4
// 199.918 us; speedup vs baseline: 1.0682x; 1.0415x over previous
//
#include <hip/hip_runtime.h>

namespace {
constexpr int CC    = 10;                  // cluster gap window C
constexpr int TT    = 500;                 // time steps
constexpr int NN    = 128;                 // neurons per batch row
constexpr int G     = 10;                  // t-segments per trace
constexpr int LSEG  = TT / G;              // 50 core steps
constexpr int HALO  = CC;                  // 10
constexpr int ROWS  = LSEG + 2 * HALO;     // 70 scanned rows per segment
constexpr int CHR   = 16;                  // rows per LDS chunk (8 KB)
constexpr int NSLOT = 10;                  // ws slots per (seg, neuron)
constexpr int MAXG  = TT / (CC + 1) + 1;   // 46 max global clusters
}

__global__ void zero_loss_kernel(float* out) {
    if (threadIdx.x == 0) out[0] = 0.0f;
}

// ---------------- kernel A: per-segment exact scan, LDS-staged ----------------
__global__ __launch_bounds__(128)
void seg_scan_kernel(const float* __restrict__ vmem, float* __restrict__ ws) {
    const int s   = blockIdx.x;            // segment 0..9
    const int b   = blockIdx.y;
    const int tid = threadIdx.x;           // neuron 0..127
    const int a   = s * LSEG;
    const int lo  = a - HALO;              // first loaded row (may be <0; clamped)
    const float* __restrict__ base = vmem + (size_t)b * TT * NN;
    float* __restrict__ wsl = ws + ((size_t)(b * G + s) * NSLOT) * NN + tid;

    __shared__ __align__(16) float buf[2][CHR * NN];   // double-buffered 8 KB tiles

    float4 ra[4], rb[4];

    auto issue = [&](int c, float4 (&r)[4]) {          // chunk c -> regs (coalesced float4)
        #pragma unroll
        for (int i = 0; i < 4; ++i) {
            const int f = tid + 128 * i;               // float4 index in 16x128 tile
            int row = lo + c * CHR + (f >> 5);
            row = row < 0 ? 0 : (row > TT - 1 ? TT - 1 : row);   // clamp; garbage masked in scan
            r[i] = *((const float4*)(base + (size_t)row * NN) + (f & 31));
        }
    };
    auto commit = [&](int c, const float4 (&r)[4]) {   // regs -> LDS
        float4* d = (float4*)buf[c & 1];
        #pragma unroll
        for (int i = 0; i < 4; ++i) d[tid + 128 * i] = r[i];
    };

    // exact per-segment scan state
    int   ls = -(1 << 20), lcount = 0, hdne = 0, tmn = 0, hasu = 0;
    float ccm = -1e30f, rmax = -1e30f, hdm = -1e30f, vmx = -1e30f, m0 = -1e30f;
    float ring[10];                                    // v delay line, static-indexed

    auto scanChunk = [&](int c) {
        const float* bsrc = buf[c & 1];
        #pragma unroll
        for (int j = 0; j < CHR; ++j) {
            const int r = c * CHR + j;                 // compile-time after inline
            if (r >= ROWS) continue;                   // prune rows 70..79
            const int ofs = r - HALO;                  // t - a in [-10, 60)
            const int t   = a + ofs;
            float v = bsrc[j * NN + tid];
            if (ofs < 0 && s == 0) v = -1.0f;          // before t=0
            if (ofs >= LSEG && s == G - 1) v = -1.0f;  // past t=T
            const bool spike = v >= 0.0f;
            if (ofs >= 0 && ofs < LSEG) {              // core accounting
                const float rm2 = fmaxf(rmax, v);
                if (spike) {
                    if (t - ls > CC) {                 // exact: halo gives full C history
                        if (lcount > 0) wsl[(size_t)(lcount - 1) * NN] = ccm;
                        ccm = v; ++lcount;
                    } else if (lcount == 0) { hdne = 1; hdm = fmaxf(hdm, rm2); }
                    else ccm = fmaxf(ccm, rm2);
                    rmax = -1e30f;
                } else rmax = rm2;
                if (v > vmx) { vmx = v; tmn = t; }     // strict > keeps first argmax
            }
            if (spike) ls = t;                         // halo spikes count for ls
            if (r >= 2 * HALO) {                       // eval u = t-10 in [a, a+50)
                const float vu = ring[r % 10];
                if (ls < t - 2 * CC) { hasu = 1; if (vu > m0) m0 = vu; }
            }
            ring[r % 10] = v;
        }
    };

    // pipeline: issue k+1 ahead of scan k; one barrier per chunk
    issue(0, ra); commit(0, ra);
    issue(1, rb);
    __syncthreads();
    scanChunk(0);
    commit(1, rb); __syncthreads();
    issue(2, ra);
    scanChunk(1);
    commit(2, ra); __syncthreads();
    issue(3, rb);
    scanChunk(2);
    commit(3, rb); __syncthreads();
    issue(4, ra);
    scanChunk(3);
    commit(4, ra); __syncthreads();
    scanChunk(4);

    if (lcount > 0) wsl[(size_t)(lcount - 1) * NN] = ccm;   // close final cluster
    const int packed = lcount | (hdne << 3) | (hasu << 4) | (tmn << 5);
    wsl[5 * NN] = __int_as_float(packed);
    wsl[6 * NN] = hdm;     // head-piece max
    wsl[7 * NN] = rmax;    // tail gap max (since last core spike)
    wsl[8 * NN] = vmx;
    wsl[9 * NN] = m0;
}

// ---------------- kernel B: merge segments + loss ----------------
__global__ __launch_bounds__(128)
void merge_kernel(const float* __restrict__ vmem, const float* __restrict__ ws,
                  const int* __restrict__ labels, float* __restrict__ out) {
    const int b = blockIdx.x; const int tid = threadIdx.x;
    __shared__ float gl[MAXG * NN];        // 23.5 KB: compact global cluster-max list
    __shared__ float redbuf[2];
    const float* __restrict__ col = vmem + (size_t)b * TT * NN + tid;

    int g_nc = 0, g_hasu = 0, g_tm = 0;
    float g_vmax = -1e30f, g_m0 = -1e30f;
    int g = 0; bool open = false; float cur = -1e30f, ptg = -1e30f;

    #pragma unroll
    for (int s2 = 0; s2 < G; ++s2) {
        const float* wsl = ws + ((size_t)(b * G + s2) * NSLOT) * NN + tid;
        const int packed = __float_as_int(wsl[5 * NN]);
        const int k = packed & 7, hne = (packed >> 3) & 1, hu = (packed >> 4) & 1;
        const int tms = packed >> 5;
        const float hdm = wsl[6 * NN], tg = wsl[7 * NN];
        const float vmx = wsl[8 * NN], m0s = wsl[9 * NN];
        g_nc += k; g_hasu |= hu;
        if (vmx > g_vmax) { g_vmax = vmx; g_tm = tms; }  // earliest argmax wins ties
        if (m0s > g_m0) g_m0 = m0s;
        if (open) {
            if (hne) { cur = fmaxf(cur, fmaxf(ptg, hdm)); ptg = tg; }
            if (k > 0 || !hne) { gl[g * NN + tid] = cur; ++g; open = false; }
        }
        if (k > 0) {
            for (int i = 0; i < k - 1; ++i) { gl[g * NN + tid] = wsl[(size_t)i * NN]; ++g; }
            cur = wsl[(size_t)(k - 1) * NN];
            open = true; ptg = tg;
        }
    }
    if (open) { gl[g * NN + tid] = cur; ++g; }           // g == g_nc

    const int label = labels[b * NN + tid];
    float contrib = 0.0f;
    if (label > g_nc) {
        if (!g_hasu) {
            contrib = g_vmax;                            // full0 -> vmax
        } else {
            float mrest = g_vmax;                        // full2 surrogate
            const bool need2 = (label - g_nc >= 2);
            if (__any((int)need2)) {
                if (need2) {                             // rare serial rescan (L3-warm)
                    const int wlo = g_tm - CC / 2, whi = g_tm + CC / 2;
                    int ls2 = -(1 << 20); float m2 = -1e30f; int has2 = 0;
                    for (int c = 0; c < TT / CC + 1; ++c) {
                        float cv[CC], pv[CC];
                        #pragma unroll
                        for (int j = 0; j < CC; ++j) {
                            const int t = c * CC + j;
                            cv[j] = (t < TT) ? col[(size_t)t * NN] : -1.0f;
                        }
                        #pragma unroll
                        for (int j = 0; j < CC; ++j) {
                            const int u = c * CC + j - CC;
                            pv[j] = (u >= 0 && u < TT) ? col[(size_t)u * NN] : -1.0f;
                        }
                        #pragma unroll
                        for (int j = 0; j < CC; ++j) {
                            const int t = c * CC + j;
                            if (cv[j] >= 0.0f) ls2 = t;
                            const int u = t - CC;
                            if (u >= 0 && u < TT) {
                                if (ls2 < t - 2 * CC && (u < wlo || u > whi)) {
                                    has2 = 1; if (pv[j] > m2) m2 = pv[j];
                                }
                            }
                        }
                    }
                    if (has2) mrest = m2;
                }
            }
            const float dE = (float)(label - g_nc);      // >= 1
            contrib = -((g_m0 + (dE - 1.0f) * mrest) / dE);
        }
    } else if (label < g_nc) {
        const int kk = g_nc - label;                     // 1..nc
        float ssum = 0.0f;
        for (int i = 0; i < kk; ++i) {                   // sum kk smallest cluster maxes
            float mn = 1e30f; int mj = 0;
            for (int jj = 0; jj < g_nc; ++jj) {
                const float x = gl[jj * NN + tid];
                if (x < mn) { mn = x; mj = jj; }
            }
            ssum += mn; gl[mj * NN + tid] = 1e30f;
        }
        contrib = ssum / (float)kk;
    }

    out[1 + b * NN + tid] = (float)g_nc;                 // spike_output

    float w = contrib;
    #pragma unroll
    for (int off = 32; off > 0; off >>= 1) w += __shfl_down(w, off, 64);
    if ((tid & 63) == 0) redbuf[tid >> 6] = w;
    __syncthreads();
    if (tid == 0) atomicAdd(out, redbuf[0] + redbuf[1]);
}

extern "C" void kernel_launch(void* const* d_in, const int* in_sizes, int n_in,
                              void* d_out, int out_size, void* d_ws, size_t ws_size,
                              hipStream_t stream) {
    const float* vmem   = (const float*)d_in[0];
    // d_in[1] (vlastmem) and d_in[3] (ratio) are unused by the reference forward.
    const int*   labels = (const int*)d_in[2];
    float*       out    = (float*)d_out;
    float*       ws     = (float*)d_ws;   // needs 256*10*10*128*4 = 13.1 MB

    const int B = in_sizes[2] / NN;       // 256

    hipLaunchKernelGGL(zero_loss_kernel, dim3(1), dim3(64), 0, stream, out);
    hipLaunchKernelGGL(seg_scan_kernel, dim3(G, B), dim3(NN), 0, stream, vmem, ws);
    hipLaunchKernelGGL(merge_kernel, dim3(B), dim3(NN), 0, stream, vmem, ws, labels, out);
}

// Round 5
// 172.501 us; speedup vs baseline: 1.2380x; 1.1589x over previous
//
#include <hip/hip_runtime.h>

namespace {
constexpr int CC    = 10;                  // cluster gap window C
constexpr int TT    = 500;                 // time steps
constexpr int NN    = 128;                 // neurons per batch row
constexpr int G     = 10;                  // t-segments per trace
constexpr int LSEG  = TT / G;              // 50 core steps
constexpr int HALO  = CC;                  // 10
constexpr int LROWS = 72;                  // rows staged in LDS (covers [-10,60) + align)
constexpr int NF4   = (LROWS * NN / 4) / NN;  // 18 float4 per thread
constexpr int NSLOT = 10;                  // ws record: 5 cluster maxes + 5 scalars
constexpr int MAXG  = TT / (CC + 1) + 1;   // 46 max global clusters
}

// ---------------- kernel A: per-segment exact scan, bulk-staged ----------------
__global__ __launch_bounds__(128, 2)
void seg_scan_kernel(const float* __restrict__ vmem, float* __restrict__ ws) {
    const int s   = blockIdx.x;            // segment 0..9
    const int b   = blockIdx.y;
    const int tid = threadIdx.x;           // neuron 0..127
    const int a   = s * LSEG;
    int ldstart = a - HALO;                // clamp the 72-row window into [0,500)
    ldstart = ldstart < 0 ? 0 : ldstart;
    ldstart = ldstart > TT - LROWS ? TT - LROWS : ldstart;
    const int shift = a - ldstart;         // buf row of t = a + ofs is ofs + shift

    __shared__ __align__(16) float buf[LROWS * NN];   // 36 KB -> 4 blocks/CU
    __shared__ float stg[5 * NN];                     // cluster-max staging (2.5 KB)

    // ---- bulk load: ALL 18 float4 issued before any wait; commit; one barrier ----
    const float4* __restrict__ g4 =
        (const float4*)(vmem + ((size_t)b * TT + ldstart) * NN);
    float4 r[NF4];
    #pragma unroll
    for (int i = 0; i < NF4; ++i) r[i] = g4[tid + NN * i];
    #pragma unroll
    for (int i = 0; i < 5; ++i) stg[i * NN + tid] = 0.0f;   // benign init
    float4* l4 = (float4*)buf;
    #pragma unroll
    for (int i = 0; i < NF4; ++i) l4[tid + NN * i] = r[i];
    __syncthreads();

    // ---- exact segment scan over ofs in [-10, 60) ----
    int   ls = -(1 << 20), lcount = 0, hdne = 0, tmn = 0, hasu = 0;
    float ccm = -1e30f, rmax = -1e30f, hdm = -1e30f, vmx = -1e30f, m0 = -1e30f;
    const bool firstSeg = (s == 0), lastSeg = (s == G - 1);

    #pragma unroll
    for (int ofs = -HALO; ofs < LSEG + HALO; ++ofs) {
        const int t = a + ofs;
        const bool invalid = (firstSeg && ofs < 0) || (lastSeg && ofs >= LSEG);
        const float v = invalid ? -1.0f : buf[(ofs + shift) * NN + tid];
        const bool spike = v >= 0.0f;
        if (ofs >= 0 && ofs < LSEG) {                 // core accounting
            const float rm2 = fmaxf(rmax, v);
            if (spike) {
                if (t - ls > CC) {                    // exact: halo gives C history
                    if (lcount > 0) stg[(lcount - 1) * NN + tid] = ccm;
                    ccm = v; ++lcount;
                } else if (lcount == 0) { hdne = 1; hdm = fmaxf(hdm, rm2); }
                else ccm = fmaxf(ccm, rm2);
                rmax = -1e30f;
            } else rmax = rm2;
            if (v > vmx) { vmx = v; tmn = t; }        // strict > keeps first argmax
        }
        if (spike) ls = t;                            // halo spikes count for ls
        if (ofs >= HALO) {                            // eval u = t-10 in [a, a+50)
            const float vu = buf[(ofs - HALO + shift) * NN + tid];
            if (ls < t - 2 * CC) { hasu = 1; if (vu > m0) m0 = vu; }
        }
    }
    if (lcount > 0) stg[(lcount - 1) * NN + tid] = ccm;

    // ---- coalesced output: 10 rows of 512 B ----
    float* __restrict__ wsl = ws + (size_t)(b * G + s) * NSLOT * NN + tid;
    #pragma unroll
    for (int i = 0; i < 5; ++i) wsl[i * NN] = stg[i * NN + tid];
    const int packed = lcount | (hdne << 3) | (hasu << 4) | (tmn << 5);
    wsl[5 * NN] = __int_as_float(packed);
    wsl[6 * NN] = hdm;     // head-piece max
    wsl[7 * NN] = rmax;    // tail gap max (since last core spike)
    wsl[8 * NN] = vmx;
    wsl[9 * NN] = m0;
}

// ---------------- kernel B: merge segments + loss ----------------
__global__ __launch_bounds__(128, 2)
void merge_kernel(const float* __restrict__ vmem, const float* __restrict__ ws,
                  const int* __restrict__ labels, float* __restrict__ out) {
    const int b = blockIdx.x, tid = threadIdx.x, lane = tid & 63;
    __shared__ float gl[MAXG * NN];        // 23.5 KB compact global cluster list
    __shared__ float wbuf[2][512];         // pass-2 column staging, one per wave
    __shared__ float red[2];

    // ---- bulk load all 100 ws values into registers (compile-time indices) ----
    float cm[G][5], hd[G], tg[G], vx[G], mm[G]; int pk[G];
    const float* __restrict__ wsb = ws + (size_t)b * G * NSLOT * NN + tid;
    #pragma unroll
    for (int s2 = 0; s2 < G; ++s2) {
        const float* p = wsb + (size_t)s2 * NSLOT * NN;
        #pragma unroll
        for (int i = 0; i < 5; ++i) cm[s2][i] = p[i * NN];
        pk[s2] = __float_as_int(p[5 * NN]);
        hd[s2] = p[6 * NN];
        tg[s2] = p[7 * NN];
        vx[s2] = p[8 * NN];
        mm[s2] = p[9 * NN];
    }

    // ---- stitch boundary-crossing clusters (round-4 verified semantics) ----
    int g = 0, g_nc = 0, g_hasu = 0, g_tm = 0;
    bool open = false; float cur = -1e30f, ptg = -1e30f;
    float g_vmax = -1e30f, g_m0 = -1e30f;
    #pragma unroll
    for (int s2 = 0; s2 < G; ++s2) {
        const int k   = pk[s2] & 7;
        const int hne = (pk[s2] >> 3) & 1;
        g_nc += k; g_hasu |= (pk[s2] >> 4) & 1;
        if (vx[s2] > g_vmax) { g_vmax = vx[s2]; g_tm = pk[s2] >> 5; }
        if (mm[s2] > g_m0) g_m0 = mm[s2];
        if (open) {
            if (hne) { cur = fmaxf(cur, fmaxf(ptg, hd[s2])); ptg = tg[s2]; }
            if (k > 0 || !hne) { gl[g * NN + tid] = cur; ++g; open = false; }
        }
        if (k > 0) {
            #pragma unroll
            for (int i = 0; i < 4; ++i)
                if (i < k - 1) { gl[g * NN + tid] = cm[s2][i]; ++g; }
            float last = cm[s2][4];                    // select cm[s2][k-1]
            if (k == 1) last = cm[s2][0];
            else if (k == 2) last = cm[s2][1];
            else if (k == 3) last = cm[s2][2];
            else if (k == 4) last = cm[s2][3];
            cur = last; open = true; ptg = tg[s2];
        }
    }
    if (open) { gl[g * NN + tid] = cur; ++g; }         // g == g_nc

    const int label = labels[b * NN + tid];

    // ---- pass-2 m_rest: wave-cooperative, rare (all 64 lanes active here) ----
    const bool need2 = (label > g_nc) && g_hasu && (label - g_nc >= 2);
    float mrest = g_vmax;                              // full2 surrogate default
    unsigned long long bal = __ballot(need2);
    if (bal) {
        float* wb = wbuf[tid >> 6];
        const float* colbase = vmem + (size_t)b * TT * NN;
        while (bal) {
            const int f = __ffsll((unsigned long long)bal) - 1;
            bal &= bal - 1;
            const int   nf    = (tid & 64) | f;        // flagged neuron index
            const int   tmf   = __shfl(g_tm, f);
            const float vmaxf = __shfl(g_vmax, f);
            #pragma unroll
            for (int j = 0; j < 8; ++j) {              // stage column: 8 loads/lane
                const int t = lane * 8 + j;
                wb[t] = (t < TT) ? colbase[(size_t)t * NN + nf] : -1.0f;
            }
            __threadfence_block();                     // drain LDS writes (wave-local)
            int ls2 = -1000, lh = 0; float lm = -1e30f;
            const int u0 = lane * 8;
            for (int t2 = u0 - 10; t2 < u0 + 18; ++t2) {
                const float v = (t2 >= 0 && t2 < 512) ? wb[t2] : -1.0f;
                if (v >= 0.0f) ls2 = t2;
                const int u = t2 - 10;
                if (u >= u0 && u < u0 + 8 && u < TT) {
                    if (ls2 < u - 10 && (u < tmf - CC / 2 || u > tmf + CC / 2)) {
                        lh = 1; const float vu = wb[u]; if (vu > lm) lm = vu;
                    }
                }
            }
            #pragma unroll
            for (int off = 32; off > 0; off >>= 1) {   // wave reduce
                lm = fmaxf(lm, __shfl_down(lm, off));
                lh |= __shfl_down(lh, off);
            }
            const float res = __shfl(lh ? lm : vmaxf, 0);
            if (lane == f) mrest = res;
            __threadfence_block();                     // wb reads done before reuse
        }
    }

    // ---- branch select ----
    float contrib = 0.0f;
    if (label > g_nc) {
        if (!g_hasu) contrib = g_vmax;                 // full0 -> vmax
        else {
            const float dE = (float)(label - g_nc);    // >= 1
            contrib = -((g_m0 + (dE - 1.0f) * mrest) / dE);
        }
    } else if (label < g_nc) {
        const int kk = g_nc - label;                   // 1..nc
        float ssum = 0.0f;
        for (int i = 0; i < kk; ++i) {                 // sum kk smallest cluster maxes
            float mn = 1e30f; int mj = 0;
            for (int jj = 0; jj < g_nc; ++jj) {
                const float x = gl[jj * NN + tid];
                if (x < mn) { mn = x; mj = jj; }
            }
            ssum += mn; gl[mj * NN + tid] = 1e30f;
        }
        contrib = ssum / (float)kk;
    }

    out[1 + b * NN + tid] = (float)g_nc;               // spike_output

    float w = contrib;
    #pragma unroll
    for (int off = 32; off > 0; off >>= 1) w += __shfl_down(w, off);
    if (lane == 0) red[tid >> 6] = w;
    __syncthreads();
    if (tid == 0) atomicAdd(out, red[0] + red[1]);
}

extern "C" void kernel_launch(void* const* d_in, const int* in_sizes, int n_in,
                              void* d_out, int out_size, void* d_ws, size_t ws_size,
                              hipStream_t stream) {
    const float* vmem   = (const float*)d_in[0];
    // d_in[1] (vlastmem) and d_in[3] (ratio) are unused by the reference forward.
    const int*   labels = (const int*)d_in[2];
    float*       out    = (float*)d_out;
    float*       ws     = (float*)d_ws;   // 256*10*10*128*4 = 13.1 MB

    const int B = in_sizes[2] / NN;       // 256

    hipMemsetAsync(out, 0, sizeof(float), stream);     // zero the loss accumulator
    hipLaunchKernelGGL(seg_scan_kernel, dim3(G, B), dim3(NN), 0, stream, vmem, ws);
    hipLaunchKernelGGL(merge_kernel, dim3(B), dim3(NN), 0, stream, vmem, ws, labels, out);
}

// Round 6
// 164.509 us; speedup vs baseline: 1.2981x; 1.0486x over previous
//
#include <hip/hip_runtime.h>

namespace {
constexpr int CC    = 10;                  // cluster gap window C
constexpr int TT    = 500;                 // time steps
constexpr int NN    = 128;                 // neurons per batch row
constexpr int G     = 10;                  // t-segments per trace
constexpr int LSEG  = TT / G;              // 50 core steps
constexpr int HALO  = CC;                  // 10
constexpr int NSLOT = 10;                  // ws record: 5 cluster maxes + 5 scalars
constexpr int MAXG  = TT / (CC + 1) + 1;   // 46 max global clusters
}

// ---------------- kernel A: per-segment scan, register-pipelined column loads ----------------
// No big LDS: occupancy capped only by VGPRs -> ~5 waves/SIMD; all 2560 blocks co-resident.
__global__ __launch_bounds__(128, 5)
void seg_scan_kernel(const float* __restrict__ vmem, float* __restrict__ ws) {
    const int s   = blockIdx.x;            // segment 0..9
    const int b   = blockIdx.y;
    const int tid = threadIdx.x;           // neuron 0..127
    const int a   = s * LSEG;
    const float* __restrict__ col = vmem + (size_t)b * TT * NN + tid;

    __shared__ float stg[5 * NN];          // 2.5 KB: cluster-max staging only

    // chunk c covers ofs = -10+10c .. -1+10c (7 chunks span [-10, 60))
    float b0[10], b1[10], b2[10], b3[10] = {};
    auto load = [&](float (&d)[10], int c) {
        #pragma unroll
        for (int j = 0; j < 10; ++j) {
            int t = a + (-HALO + 10 * c + j);
            t = t < 0 ? 0 : (t > TT - 1 ? TT - 1 : t);   // clamp; masked in scan
            d[j] = col[(size_t)t * NN];
        }
    };

    int   ls = -(1 << 20), lcount = 0, hdne = 0, tmn = 0, hasu = 0;
    float ccm = -1e30f, rmax = -1e30f, hdm = -1e30f, vmx = -1e30f, m0 = -1e30f;
    const bool firstSeg = (s == 0), lastSeg = (s == G - 1);
    #pragma unroll
    for (int i = 0; i < 5; ++i) stg[i * NN + tid] = 0.0f;

    auto scan = [&](const float (&cur)[10], const float (&prev)[10], int c) {
        #pragma unroll
        for (int j = 0; j < 10; ++j) {
            const int ofs = -HALO + 10 * c + j;   // compile-time
            const int t   = a + ofs;
            float v = cur[j];
            if ((ofs < 0 && firstSeg) || (ofs >= LSEG && lastSeg)) v = -1.0f;
            const bool spike = v >= 0.0f;
            if (ofs >= 0 && ofs < LSEG) {                 // core accounting
                const float rm2 = fmaxf(rmax, v);
                if (spike) {
                    if (t - ls > CC) {                    // halo gives full C history
                        if (lcount > 0) stg[(lcount - 1) * NN + tid] = ccm;
                        ccm = v; ++lcount;
                    } else if (lcount == 0) { hdne = 1; hdm = fmaxf(hdm, rm2); }
                    else ccm = fmaxf(ccm, rm2);
                    rmax = -1e30f;
                } else rmax = rm2;
                if (v > vmx) { vmx = v; tmn = t; }        // strict >: first argmax
            }
            if (spike) ls = t;                            // halo spikes count for ls
            if (ofs >= HALO) {                            // eval u = t-10 in [a, a+50)
                const float vu = prev[j];                 // v[t-10] = prev chunk same j
                if (ls < t - 2 * CC) { hasu = 1; if (vu > m0) m0 = vu; }
            }
        }
    };

    // distance-2 register pipeline over 7 chunks (scan c needs chunks c and c-1)
    load(b0, 0); load(b1, 1);
    load(b2, 2); scan(b0, b3, 0);   // prev unused at c=0 (ofs<10 compile-time)
    load(b3, 3); scan(b1, b0, 1);
    load(b0, 4); scan(b2, b1, 2);
    load(b1, 5); scan(b3, b2, 3);
    load(b2, 6); scan(b0, b3, 4);
    scan(b1, b0, 5);
    scan(b2, b1, 6);

    if (lcount > 0) stg[(lcount - 1) * NN + tid] = ccm;   // close final cluster

    // coalesced output: 10 rows of 512 B
    float* __restrict__ wsl = ws + (size_t)(b * G + s) * NSLOT * NN + tid;
    #pragma unroll
    for (int i = 0; i < 5; ++i) wsl[i * NN] = stg[i * NN + tid];
    const int packed = lcount | (hdne << 3) | (hasu << 4) | (tmn << 5);
    wsl[5 * NN] = __int_as_float(packed);
    wsl[6 * NN] = hdm;     // head-piece max
    wsl[7 * NN] = rmax;    // tail gap max (since last core spike)
    wsl[8 * NN] = vmx;
    wsl[9 * NN] = m0;
}

// ---------------- kernel B: merge segments + loss (1 wave per 64 neurons) ----------------
__global__ __launch_bounds__(64)
void merge_kernel(const float* __restrict__ vmem, const float* __restrict__ ws,
                  const int* __restrict__ labels, float* __restrict__ out) {
    const int bb = blockIdx.x, lane = threadIdx.x;
    const int b = bb >> 1, n = ((bb & 1) << 6) | lane;
    __shared__ float gl[MAXG * 64];        // 11.8 KB compact global cluster list
    __shared__ float wb[512];              // pass-2 column staging

    // streaming double-buffered ws reads: 10 values per segment in flight
    const float* __restrict__ wsb = ws + (size_t)b * G * NSLOT * NN + n;
    float f[2][10];
    auto loadSeg = [&](int slot, int s2) {
        const float* p = wsb + (size_t)s2 * NSLOT * NN;
        #pragma unroll
        for (int i = 0; i < 10; ++i) f[slot][i] = p[i * NN];
    };
    loadSeg(0, 0);

    int g = 0, g_nc = 0, g_hasu = 0, g_tm = 0;
    bool open = false; float cur = -1e30f, ptg = -1e30f;
    float g_vmax = -1e30f, g_m0 = -1e30f;
    #pragma unroll
    for (int s2 = 0; s2 < G; ++s2) {
        if (s2 + 1 < G) loadSeg((s2 + 1) & 1, s2 + 1);
        const float (&d)[10] = f[s2 & 1];
        const int pk = __float_as_int(d[5]);
        const int k = pk & 7, hne = (pk >> 3) & 1;
        g_nc += k; g_hasu |= (pk >> 4) & 1;
        if (d[8] > g_vmax) { g_vmax = d[8]; g_tm = pk >> 5; }
        if (d[9] > g_m0) g_m0 = d[9];
        if (open) {
            if (hne) { cur = fmaxf(cur, fmaxf(ptg, d[6])); ptg = d[7]; }
            if (k > 0 || !hne) { gl[g * 64 + lane] = cur; ++g; open = false; }
        }
        if (k > 0) {
            #pragma unroll
            for (int i = 0; i < 4; ++i)
                if (i < k - 1) { gl[g * 64 + lane] = d[i]; ++g; }
            float last = d[4];                 // select d[k-1]
            if (k == 1) last = d[0];
            else if (k == 2) last = d[1];
            else if (k == 3) last = d[2];
            else if (k == 4) last = d[3];
            cur = last; open = true; ptg = d[7];
        }
    }
    if (open) { gl[g * 64 + lane] = cur; ++g; }        // g == g_nc

    const int label = labels[b * NN + n];

    // pass-2 m_rest: wave-cooperative, rare
    const bool need2 = (label > g_nc) && g_hasu && (label - g_nc >= 2);
    float mrest = g_vmax;                              // full2 surrogate default
    unsigned long long bal = __ballot(need2);
    const float* colbase = vmem + (size_t)b * TT * NN;
    while (bal) {
        const int fl = __ffsll((unsigned long long)bal) - 1;
        bal &= bal - 1;
        const int   nf    = ((bb & 1) << 6) | fl;      // flagged neuron
        const int   tmf   = __shfl(g_tm, fl);
        const float vmaxf = __shfl(g_vmax, fl);
        #pragma unroll
        for (int j = 0; j < 8; ++j) {                  // stage column: 8 loads/lane
            const int t = lane * 8 + j;
            wb[t] = (t < TT) ? colbase[(size_t)t * NN + nf] : -1.0f;
        }
        __syncthreads();                               // single wave: cheap
        int ls2 = -1000, lh = 0; float lm = -1e30f;
        const int u0 = lane * 8;
        for (int t2 = u0 - 10; t2 < u0 + 18; ++t2) {
            const float v = (t2 >= 0 && t2 < 512) ? wb[t2] : -1.0f;
            if (v >= 0.0f) ls2 = t2;
            const int u = t2 - 10;
            if (u >= u0 && u < u0 + 8 && u < TT) {
                if (ls2 < u - 10 && (u < tmf - CC / 2 || u > tmf + CC / 2)) {
                    lh = 1; const float vu = wb[u]; if (vu > lm) lm = vu;
                }
            }
        }
        #pragma unroll
        for (int off = 32; off > 0; off >>= 1) {       // wave reduce
            lm = fmaxf(lm, __shfl_down(lm, off));
            lh |= __shfl_down(lh, off);
        }
        const float res = __shfl(lh ? lm : vmaxf, 0);
        if (lane == fl) mrest = res;
        __syncthreads();
    }

    // branch select
    float contrib = 0.0f;
    if (label > g_nc) {
        if (!g_hasu) contrib = g_vmax;                 // full0 -> vmax
        else {
            const float dE = (float)(label - g_nc);    // >= 1
            contrib = -((g_m0 + (dE - 1.0f) * mrest) / dE);
        }
    } else if (label < g_nc) {
        const int kk = g_nc - label;                   // 1..nc
        float ssum = 0.0f;
        for (int i = 0; i < kk; ++i) {                 // sum kk smallest cluster maxes
            float mn = 1e30f; int mj = 0;
            for (int jj = 0; jj < g_nc; ++jj) {
                const float x = gl[jj * 64 + lane];
                if (x < mn) { mn = x; mj = jj; }
            }
            ssum += mn; gl[mj * 64 + lane] = 1e30f;
        }
        contrib = ssum / (float)kk;
    }

    out[1 + b * NN + n] = (float)g_nc;                 // spike_output

    float w = contrib;
    #pragma unroll
    for (int off = 32; off > 0; off >>= 1) w += __shfl_down(w, off);
    if (lane == 0) atomicAdd(out, w);
}

extern "C" void kernel_launch(void* const* d_in, const int* in_sizes, int n_in,
                              void* d_out, int out_size, void* d_ws, size_t ws_size,
                              hipStream_t stream) {
    const float* vmem   = (const float*)d_in[0];
    // d_in[1] (vlastmem) and d_in[3] (ratio) are unused by the reference forward.
    const int*   labels = (const int*)d_in[2];
    float*       out    = (float*)d_out;
    float*       ws     = (float*)d_ws;   // 256*10*10*128*4 = 13.1 MB

    const int B = in_sizes[2] / NN;       // 256

    hipMemsetAsync(out, 0, sizeof(float), stream);     // zero the loss accumulator
    hipLaunchKernelGGL(seg_scan_kernel, dim3(G, B), dim3(NN), 0, stream, vmem, ws);
    hipLaunchKernelGGL(merge_kernel, dim3(2 * B), dim3(64), 0, stream, vmem, ws, labels, out);
}